// Round 9
// baseline (70499.738 us; speedup 1.0000x reference)
//
#include <hip/hip_runtime.h>
#include <cmath>

#define B 128
#define L 64
#define D 512
#define H 256
#define G4 1024
#define TOTROWS 2080   // 64*65/2
#define GF_PAD 16

typedef float fx4 __attribute__((ext_vector_type(4)));

__device__ __forceinline__ float sigf(float x) { return 1.0f / (1.0f + expf(-x)); }

// ---- cross-block primitives (only used once per iteration per block) ----
__device__ __forceinline__ void stg_sc_f64(double* p, double v) {
    asm volatile("global_store_dwordx2 %0, %1, off sc0 sc1" :: "v"(p), "v"(v) : "memory");
}
__device__ __forceinline__ void stg_sc_u32(int* p, int v) {
    asm volatile("global_store_dword %0, %1, off sc0 sc1" :: "v"(p), "v"(v) : "memory");
}
__device__ __forceinline__ int ld_flag_bypass(const int* p) {
    int v;
    asm volatile("global_load_dword %0, %1, off sc0 sc1\n\ts_waitcnt vmcnt(0)"
                 : "=v"(v) : "v"(p) : "memory");
    return v;
}
__device__ __forceinline__ double ldg_sc_f64(const double* p) {
    double v;
    asm volatile("global_load_dwordx2 %0, %1, off sc0 sc1\n\ts_waitcnt vmcnt(0)"
                 : "=v"(v) : "v"(p) : "memory");
    return v;
}

// ---------------- init: uh0 -> units chunk (len=64); zero flags ----------------
__global__ __launch_bounds__(256) void k_init(const int* __restrict__ ex_in,
                                              const float* __restrict__ uh_in,
                                              float* __restrict__ units,
                                              int* __restrict__ flags) {
    int idx = blockIdx.x * 256 + threadIdx.x;   // over B*L*(D/4) = 1,048,576
    if (idx < 8192) flags[idx] = 0;
    int bt = idx >> 7;
    int r  = idx & 127;
    float m = (ex_in[bt] != 0) ? 1.0f : 0.0f;
    const float4* src = (const float4*)uh_in;
    float4 v = src[idx];
    v.x *= m; v.y *= m; v.z *= m; v.w *= m;
    int b = bt >> 6, t = bt & 63;
    float4* dst = (float4*)units;
    dst[((size_t)b * TOTROWS + 2016 + t) * 128 + r] = v;
}

// ---------------- one-time: W_ih transposed to [d][k][1024] ----------------
__global__ __launch_bounds__(256) void k_wprep_ih(const float* __restrict__ wf,
                                                  const float* __restrict__ wb,
                                                  float* __restrict__ wt) {
    int o = blockIdx.x * 256 + threadIdx.x;   // 2*512*1024
    int n = o & 1023;
    int k = (o >> 10) & 511;
    int d = o >> 19;
    const float* W = d ? wb : wf;
    wt[o] = W[n * 512 + k];
}

// ---------------- one-time: W_hh -> coalesced per-thread-row layout -----------
// wt4[(d*64 + m)*1024 + jt] (float4) = W[d][row jt][4m .. 4m+3]
__global__ __launch_bounds__(256) void k_wprep_hh(const float* __restrict__ wf,
                                                  const float* __restrict__ wb,
                                                  float* __restrict__ wt) {
    int o = blockIdx.x * 256 + threadIdx.x;   // 2*64*1024*4 = 524,288 floats
    int c  = o & 3;
    int f  = o >> 2;
    int jt = f & 1023;
    int m  = (f >> 10) & 63;
    int dd = f >> 16;
    const float* W = dd ? wb : wf;
    wt[o] = W[jt * 256 + m * 4 + c];
}

// ---------------- one-time full xg = uh0 @ W_ih^T (len=64) ----------------
__global__ __launch_bounds__(256) void k_xg(const float* __restrict__ units,
                                            const float* __restrict__ wihT,
                                            float* __restrict__ xg, int len, int offL) {
    __shared__ __align__(16) float As[32 * 132];
    __shared__ __align__(16) float Bs[32 * 132];
    int tid = threadIdx.x;
    int nt = blockIdx.x, mtb = blockIdx.y;
    int d = nt >> 3;
    int gbase = (nt & 7) * 128;
    int M = 128 * len;

    int arow = tid & 127, ahalf = tid >> 7;
    int agm = mtb * 128 + arow;
    const float* aptr = nullptr;
    if (agm < M) {
        int ab = agm / len, at = agm - ab * len;
        aptr = units + ((size_t)ab * TOTROWS + offL + at) * 512;
    }
    int bcol = (tid & 31) * 4, bkr = tid >> 5;
    int tm = tid >> 4, tn = tid & 15;

    float acc[8][8];
#pragma unroll
    for (int i = 0; i < 8; i++)
#pragma unroll
        for (int j = 0; j < 8; j++) acc[i][j] = 0.f;

    for (int k0 = 0; k0 < 512; k0 += 32) {
#pragma unroll
        for (int i4 = 0; i4 < 4; i4++) {
            float4 v;
            if (aptr) v = *(const float4*)&aptr[k0 + ahalf * 16 + i4 * 4];
            else { v.x = v.y = v.z = v.w = 0.f; }
            int kk = ahalf * 16 + i4 * 4;
            As[(kk + 0) * 132 + arow] = v.x;
            As[(kk + 1) * 132 + arow] = v.y;
            As[(kk + 2) * 132 + arow] = v.z;
            As[(kk + 3) * 132 + arow] = v.w;
        }
#pragma unroll
        for (int i = 0; i < 4; i++) {
            int kk = bkr * 4 + i;
            float4 v = *(const float4*)&wihT[((size_t)(d * 512 + k0 + kk)) * 1024 + gbase + bcol];
            *(float4*)&Bs[kk * 132 + bcol] = v;
        }
        __syncthreads();
#pragma unroll 4
        for (int k = 0; k < 32; k++) {
            float4 a0 = *(const float4*)&As[k * 132 + tm * 8];
            float4 a1 = *(const float4*)&As[k * 132 + tm * 8 + 4];
            float4 b0 = *(const float4*)&Bs[k * 132 + tn * 8];
            float4 b1 = *(const float4*)&Bs[k * 132 + tn * 8 + 4];
            float av[8] = {a0.x, a0.y, a0.z, a0.w, a1.x, a1.y, a1.z, a1.w};
            float bv[8] = {b0.x, b0.y, b0.z, b0.w, b1.x, b1.y, b1.z, b1.w};
#pragma unroll
            for (int i = 0; i < 8; i++)
#pragma unroll
                for (int j = 0; j < 8; j++) acc[i][j] = fmaf(av[i], bv[j], acc[i][j]);
        }
        __syncthreads();
    }
#pragma unroll
    for (int i = 0; i < 8; i++) {
        int gm = mtb * 128 + tm * 8 + i;
        if (gm < M) {
            int bb = gm / len, tt = gm - bb * len;
            float* Cp = xg + ((size_t)(d * B + bb) * L + tt) * G4 + gbase + tn * 8;
            float4 v0; v0.x = acc[i][0]; v0.y = acc[i][1]; v0.z = acc[i][2]; v0.w = acc[i][3];
            float4 v1; v1.x = acc[i][4]; v1.y = acc[i][5]; v1.z = acc[i][6]; v1.w = acc[i][7];
            *(float4*)&Cp[0] = v0;
            *(float4*)&Cp[4] = v1;
        }
    }
}

// ---------------- chain kernel: one block (1024 thr) per (d,b) chain -----------
// Thread jt owns gate row jt (W row in 256 VGPRs). h exchanged via LDS only.
// Cross-block: one o-exchange with the partner direction per iteration.
__global__ __launch_bounds__(1024, 4) void k_chain(
        float* __restrict__ xg, const float* __restrict__ wtHH,
        const float* __restrict__ bias_f, const float* __restrict__ bias_b,
        const float* __restrict__ ow, const float* __restrict__ h0,
        const float* __restrict__ c0, const int* __restrict__ ex_in,
        double* __restrict__ opart, const float* __restrict__ obias,
        float* __restrict__ units, float* __restrict__ out_or,
        float* __restrict__ out_ex, int* flags) {
    __shared__ __align__(16) float hs[256];
    __shared__ __align__(16) float gates[1024];
    __shared__ double psum[4];
    __shared__ double o_own[64];
    __shared__ float osh[64];
    __shared__ float dsh[64];
    __shared__ float exl[64];
    int jt = threadIdx.x;
    int bid = blockIdx.x;
    int d = bid >> 7, b = bid & 127;

    // W row -> registers (coalesced via prepped layout)
    float4 w[64];
    {
        const float4* wp = (const float4*)wtHH + (size_t)d * 65536 + jt;
#pragma unroll
        for (int m = 0; m < 64; m++) w[m] = wp[(size_t)m * 1024];
    }
    float biasv = (d ? bias_b : bias_f)[jt];
    float owv = 0.f, h0v = 0.f, c0v = 0.f;
    if (jt < 256) {
        owv = ow[d * H + jt];
        h0v = h0[d * H + jt];
        c0v = c0[d * H + jt];
    }
    if (jt < 64) exl[jt] = (ex_in[b * 64 + jt] != 0) ? 1.0f : 0.0f;
    float* xgm = xg + (size_t)(d * 128 + b) * 65536;   // [t][jt]
    float ob0 = obias[0];

    for (int it = 0; it < 64; ++it) {
        int len = 64 - it;
        int offL = len * (len - 1) / 2;
        int n = len - 1;

        // ---- recurrence, fully block-local ----
        float c_reg = c0v;
        if (jt < 256) hs[jt] = h0v;
        __syncthreads();
        int t0 = d ? n : 0;
        float xg_cur = xgm[t0 * 1024 + jt];
        for (int s = 0; s < len; ++s) {
            int t = d ? (n - s) : s;
            float xg_nxt = 0.f;
            if (s + 1 < len) {
                int tn2 = d ? (n - s - 1) : (s + 1);
                xg_nxt = xgm[tn2 * 1024 + jt];
            }
            // dot: g[jt] = sum_k hs[k] * W[jt][k]
            float a0 = 0.f, a1 = 0.f, a2 = 0.f, a3 = 0.f;
#pragma unroll
            for (int m = 0; m < 64; m += 4) {
                float4 hc0 = *(const float4*)&hs[(m + 0) * 4];
                float4 hc1 = *(const float4*)&hs[(m + 1) * 4];
                float4 hc2 = *(const float4*)&hs[(m + 2) * 4];
                float4 hc3 = *(const float4*)&hs[(m + 3) * 4];
                float4 w0 = w[m + 0], w1 = w[m + 1], w2 = w[m + 2], w3 = w[m + 3];
                a0 = fmaf(hc0.x, w0.x, a0); a0 = fmaf(hc0.y, w0.y, a0);
                a0 = fmaf(hc0.z, w0.z, a0); a0 = fmaf(hc0.w, w0.w, a0);
                a1 = fmaf(hc1.x, w1.x, a1); a1 = fmaf(hc1.y, w1.y, a1);
                a1 = fmaf(hc1.z, w1.z, a1); a1 = fmaf(hc1.w, w1.w, a1);
                a2 = fmaf(hc2.x, w2.x, a2); a2 = fmaf(hc2.y, w2.y, a2);
                a2 = fmaf(hc2.z, w2.z, a2); a2 = fmaf(hc2.w, w2.w, a2);
                a3 = fmaf(hc3.x, w3.x, a3); a3 = fmaf(hc3.y, w3.y, a3);
                a3 = fmaf(hc3.z, w3.z, a3); a3 = fmaf(hc3.w, w3.w, a3);
            }
            gates[jt] = (xg_cur + biasv) + ((a0 + a1) + (a2 + a3));
            __syncthreads();
            // combine (threads 0..255): c,h update + o contribution
            if (jt < 256) {
                float gi = gates[jt];
                float gf = gates[256 + jt];
                float gg = gates[512 + jt];
                float go = gates[768 + jt];
                float cc = sigf(gf) * ((s == 0) ? c0v : c_reg) + sigf(gi) * tanhf(gg);
                c_reg = cc;
                float hh = sigf(go) * tanhf(cc);
                hs[jt] = hh;
                double contrib = (double)hh * (double)owv;
#pragma unroll
                for (int off = 32; off > 0; off >>= 1)
                    contrib += __shfl_xor(contrib, off);
                if ((jt & 63) == 0) psum[jt >> 6] = contrib;
            }
            __syncthreads();
            if (jt == 0) {
                double oo = (psum[0] + psum[1]) + (psum[2] + psum[3]);
                o_own[t] = oo;
                stg_sc_f64(&opart[(((size_t)((it & 1) * 2 + d) * 128 + b) << 6) + t], oo);
            }
            xg_cur = xg_nxt;
        }
        __syncthreads();   // o_own complete

        // ---- pairwise o exchange with partner direction ----
        if (jt == 0) {
            asm volatile("s_waitcnt vmcnt(0)" ::: "memory");
            stg_sc_u32(&flags[(b * 2 + d) * GF_PAD], it + 1);
            while (ld_flag_bypass(&flags[(b * 2 + (d ^ 1)) * GF_PAD]) < it + 1)
                __builtin_amdgcn_s_sleep(8);
        }
        __syncthreads();

        // ---- orient values + outputs ----
        if (jt < len) {
            double opp = ldg_sc_f64(&opart[(((size_t)((it & 1) * 2 + (d ^ 1)) * 128 + b) << 6) + jt]);
            double oo  = o_own[jt];
            double of  = (d == 0) ? oo : opp;
            double obk = (d == 0) ? opp : oo;
            float o_t = (float)(((double)ob0 + of) + obk);
            osh[jt] = o_t;
            if (d == 0) {
                out_or[(size_t)b * TOTROWS + offL + jt] = o_t;
                out_ex[(size_t)b * TOTROWS + offL + jt] = exl[jt];
            }
        }
        __syncthreads();

        // ---- decisions (replicated in both blocks) ----
        float newex = 0.f;
        if (jt < n) {
            float lw = (osh[jt] > 0.f && exl[jt] != 0.f) ? 1.f : 0.f;
            float rw = (!(osh[jt + 1] > 0.f) && exl[jt + 1] != 0.f) ? 1.f : 0.f;
            dsh[jt] = lw + 2.f * rw;
            newex = ((lw + rw) > 0.f) ? 1.f : 0.f;
        }
        __syncthreads();
        if (jt < n) exl[jt] = newex;
        __syncthreads();

        // ---- merges (thread-local columns, plain cached ops) ----
        if (n > 0) {
            {   // xg slice: column jt
                float* colp = xgm + jt;
                float cur = colp[0];
                int tt = 0;
                while (tt < n) {
                    int m8 = (n - tt < 8) ? (n - tt) : 8;
                    float nx[8];
#pragma unroll
                    for (int i = 0; i < 8; i++) if (i < m8) nx[i] = colp[(size_t)(tt + i + 1) * 1024];
#pragma unroll
                    for (int i = 0; i < 8; i++) if (i < m8) {
                        int dv = (int)dsh[tt + i];
                        colp[(size_t)(tt + i) * 1024] = (float)(dv & 1) * cur + (float)(dv >> 1) * nx[i];
                        cur = nx[i];
                    }
                    tt += m8;
                }
            }
            if (d == 0 && jt < 512) {   // units: column jt
                const float* srcp = units + ((size_t)b * TOTROWS + offL) * 512 + jt;
                float* dstp = units + ((size_t)b * TOTROWS + offL - n) * 512 + jt;
                float cur = srcp[0];
                int tt = 0;
                while (tt < n) {
                    int m8 = (n - tt < 8) ? (n - tt) : 8;
                    float nx[8];
#pragma unroll
                    for (int i = 0; i < 8; i++) if (i < m8) nx[i] = srcp[(size_t)(tt + i + 1) * 512];
#pragma unroll
                    for (int i = 0; i < 8; i++) if (i < m8) {
                        int dv = (int)dsh[tt + i];
                        dstp[(size_t)(tt + i) * 512] = (float)(dv & 1) * cur + (float)(dv >> 1) * nx[i];
                        cur = nx[i];
                    }
                    tt += m8;
                }
            }
        }
        __syncthreads();
    }
}

extern "C" void kernel_launch(void* const* d_in, const int* in_sizes, int n_in,
                              void* d_out, int out_size, void* d_ws, size_t ws_size,
                              hipStream_t stream) {
    const int*   ex_in   = (const int*)d_in[0];
    const float* uh_in   = (const float*)d_in[1];
    const float* w_ih_f  = (const float*)d_in[2];
    const float* w_hh_f  = (const float*)d_in[3];
    const float* b_f     = (const float*)d_in[4];
    const float* w_ih_b  = (const float*)d_in[5];
    const float* w_hh_b  = (const float*)d_in[6];
    const float* b_b     = (const float*)d_in[7];
    const float* orientw = (const float*)d_in[8];
    const float* orientb = (const float*)d_in[9];
    const float* h0      = (const float*)d_in[10];
    const float* c0      = (const float*)d_in[11];

    float* units  = (float*)d_out;
    float* out_or = units + (size_t)B * TOTROWS * D;
    float* out_ex = out_or + (size_t)B * TOTROWS;

    float* xg    = (float*)d_ws;                       // 16,777,216 f (64MB)
    float* wihT  = xg + (size_t)2 * B * L * G4;        // 1,048,576 f (4MB)
    float* wtHH  = wihT + (size_t)1048576;             // 524,288 f (2MB)
    double* opart = (double*)(wtHH + 524288);          // 2*2*128*64 = 32,768 d (256KB)
    int*   flags = (int*)(opart + 32768);              // 8,192 ints

    k_init<<<4096, 256, 0, stream>>>(ex_in, uh_in, units, flags);
    k_wprep_ih<<<4096, 256, 0, stream>>>(w_ih_f, w_ih_b, wihT);
    k_wprep_hh<<<2048, 256, 0, stream>>>(w_hh_f, w_hh_b, wtHH);
    k_xg<<<dim3(16, 64), 256, 0, stream>>>(units, wihT, xg, 64, 2016);
    k_chain<<<256, 1024, 0, stream>>>(xg, wtHH, b_f, b_b, orientw, h0, c0, ex_in,
                                      opart, orientb, units, out_or, out_ex, flags);
    (void)in_sizes; (void)n_in; (void)out_size; (void)ws_size;
}

// Round 10
// 12900.562 us; speedup vs baseline: 5.4649x; 5.4649x over previous
//
#include <hip/hip_runtime.h>
#include <cmath>

#define B 128
#define L 64
#define D 512
#define H 256
#define G4 1024
#define TOTROWS 2080   // 64*65/2
#define NBLK 256
#define GF_PAD 16

typedef float fx4 __attribute__((ext_vector_type(4)));

__device__ __forceinline__ float sigf(float x) { return 1.0f / (1.0f + expf(-x)); }

// ---- coherence-point (L3) stores/loads ----
__device__ __forceinline__ void stg_sc_f32(float* p, float v) {
    asm volatile("global_store_dword %0, %1, off sc0 sc1" :: "v"(p), "v"(v) : "memory");
}
__device__ __forceinline__ void stg_sc_f64(double* p, double v) {
    asm volatile("global_store_dwordx2 %0, %1, off sc0 sc1" :: "v"(p), "v"(v) : "memory");
}
__device__ __forceinline__ void stg_sc_f4(float* p, float4 v) {
    fx4 w = __builtin_bit_cast(fx4, v);
    asm volatile("global_store_dwordx4 %0, %1, off sc0 sc1" :: "v"(p), "v"(w) : "memory");
}
// 64B poll read: 4 back-to-back dwordx4 sc loads, single vmcnt drain
__device__ __forceinline__ void ld4x4_sc(const float* p, fx4& a, fx4& b, fx4& c, fx4& d) {
    asm volatile(
        "global_load_dwordx4 %0, %4, off sc0 sc1\n\t"
        "global_load_dwordx4 %1, %4, off offset:16 sc0 sc1\n\t"
        "global_load_dwordx4 %2, %4, off offset:32 sc0 sc1\n\t"
        "global_load_dwordx4 %3, %4, off offset:48 sc0 sc1\n\t"
        "s_waitcnt vmcnt(0)"
        : "=&v"(a), "=&v"(b), "=&v"(c), "=&v"(d)
        : "v"(p) : "memory");
}
__device__ __forceinline__ bool any_nan(fx4 v) {
    return (v[0] != v[0]) | (v[1] != v[1]) | (v[2] != v[2]) | (v[3] != v[3]);
}

__device__ __forceinline__ void st_flag(int* p, int v) {
    __hip_atomic_store(p, v, __ATOMIC_RELAXED, __HIP_MEMORY_SCOPE_AGENT);
}
__device__ __forceinline__ int ld_flag(const int* p) {
    return __hip_atomic_load(p, __ATOMIC_RELAXED, __HIP_MEMORY_SCOPE_AGENT);
}

// full-grid flag barrier + acquire fence (iteration boundaries only)
__device__ __forceinline__ void grid_barrier2(int* dflag, int* dgen, int bid, int phase) {
    __syncthreads();
    if (threadIdx.x == 0) {
        asm volatile("s_waitcnt vmcnt(0)" ::: "memory");
        st_flag(dflag + bid * GF_PAD, phase);
    }
    if (bid == 0) {
        if (threadIdx.x < 64) {
#pragma unroll
            for (int i = 0; i < 4; i++)
                while (ld_flag(dflag + (threadIdx.x * 4 + i) * GF_PAD) < phase)
                    __builtin_amdgcn_s_sleep(1);
        }
        __syncthreads();
        if (threadIdx.x == 0) st_flag(dgen, phase);
    } else if (threadIdx.x == 0) {
        while (ld_flag(dgen) < phase) __builtin_amdgcn_s_sleep(1);
    }
    __builtin_amdgcn_fence(__ATOMIC_ACQUIRE, "agent");
    __syncthreads();
}

// ---------------- init: uh0 -> units chunk; ex init; flags zero; hst poison ----
__global__ __launch_bounds__(256) void k_init(const int* __restrict__ ex_in,
                                              const float* __restrict__ uh_in,
                                              float* __restrict__ units,
                                              float* __restrict__ exdst,
                                              float* __restrict__ hst,
                                              int* __restrict__ flags) {
    int idx = blockIdx.x * 256 + threadIdx.x;   // over 1,048,576
    if (idx < 8192) flags[idx] = 0;
    {   // poison all 64 h slices (4,194,304 floats = idx*4)
        float qn = __uint_as_float(0x7fc00000u);
        float4 q4; q4.x = qn; q4.y = qn; q4.z = qn; q4.w = qn;
        ((float4*)hst)[idx] = q4;
    }
    int bt = idx >> 7;
    int r  = idx & 127;
    float m = (ex_in[bt] != 0) ? 1.0f : 0.0f;
    const float4* src = (const float4*)uh_in;
    float4 v = src[idx];
    v.x *= m; v.y *= m; v.z *= m; v.w *= m;
    int b = bt >> 6, t = bt & 63;
    float4* dst = (float4*)units;
    dst[((size_t)b * TOTROWS + 2016 + t) * 128 + r] = v;
    if (r == 0) exdst[bt] = m;
}

// ---------------- one-time: W_ih transposed to [d][k][1024] ----------------
__global__ __launch_bounds__(256) void k_wprep_ih(const float* __restrict__ wf,
                                                  const float* __restrict__ wb,
                                                  float* __restrict__ wt) {
    int o = blockIdx.x * 256 + threadIdx.x;   // 2*512*1024
    int n = o & 1023;
    int k = (o >> 10) & 511;
    int d = o >> 19;
    const float* W = d ? wb : wf;
    wt[o] = W[n * 512 + k];
}

// ---------------- one-time: W_hh into per-lane register layout -------------
__global__ __launch_bounds__(256) void k_wprep_hh(const float* __restrict__ wf,
                                                  const float* __restrict__ wb,
                                                  float* __restrict__ wt) {
    int o = blockIdx.x * 256 + threadIdx.x;   // 2*16*256*64
    int c    = o & 3;
    int i4   = (o >> 2) & 3;
    int q    = (o >> 4) & 3;
    int lane = (o >> 6) & 255;
    int jg   = (o >> 14) & 15;
    int d    = o >> 18;
    int jj = lane & 15, kseg = lane >> 4;
    const float* W = d ? wb : wf;
    wt[o] = W[(q * 256 + jg * 16 + jj) * 256 + kseg * 16 + i4 * 4 + c];
}

// ---------------- one-time full xg = uh0 @ W_ih^T (len=64) ----------------
__global__ __launch_bounds__(256) void k_xg(const float* __restrict__ units,
                                            const float* __restrict__ wihT,
                                            float* __restrict__ xg, int len, int offL) {
    __shared__ __align__(16) float As[32 * 132];
    __shared__ __align__(16) float Bs[32 * 132];
    int tid = threadIdx.x;
    int nt = blockIdx.x, mtb = blockIdx.y;
    int d = nt >> 3;
    int gbase = (nt & 7) * 128;
    int M = 128 * len;

    int arow = tid & 127, ahalf = tid >> 7;
    int agm = mtb * 128 + arow;
    const float* aptr = nullptr;
    if (agm < M) {
        int ab = agm / len, at = agm - ab * len;
        aptr = units + ((size_t)ab * TOTROWS + offL + at) * 512;
    }
    int bcol = (tid & 31) * 4, bkr = tid >> 5;
    int tm = tid >> 4, tn = tid & 15;

    float acc[8][8];
#pragma unroll
    for (int i = 0; i < 8; i++)
#pragma unroll
        for (int j = 0; j < 8; j++) acc[i][j] = 0.f;

    for (int k0 = 0; k0 < 512; k0 += 32) {
#pragma unroll
        for (int i4 = 0; i4 < 4; i4++) {
            float4 v;
            if (aptr) v = *(const float4*)&aptr[k0 + ahalf * 16 + i4 * 4];
            else { v.x = v.y = v.z = v.w = 0.f; }
            int kk = ahalf * 16 + i4 * 4;
            As[(kk + 0) * 132 + arow] = v.x;
            As[(kk + 1) * 132 + arow] = v.y;
            As[(kk + 2) * 132 + arow] = v.z;
            As[(kk + 3) * 132 + arow] = v.w;
        }
#pragma unroll
        for (int i = 0; i < 4; i++) {
            int kk = bkr * 4 + i;
            float4 v = *(const float4*)&wihT[((size_t)(d * 512 + k0 + kk)) * 1024 + gbase + bcol];
            *(float4*)&Bs[kk * 132 + bcol] = v;
        }
        __syncthreads();
#pragma unroll 4
        for (int k = 0; k < 32; k++) {
            float4 a0 = *(const float4*)&As[k * 132 + tm * 8];
            float4 a1 = *(const float4*)&As[k * 132 + tm * 8 + 4];
            float4 b0 = *(const float4*)&Bs[k * 132 + tn * 8];
            float4 b1 = *(const float4*)&Bs[k * 132 + tn * 8 + 4];
            float av[8] = {a0.x, a0.y, a0.z, a0.w, a1.x, a1.y, a1.z, a1.w};
            float bv[8] = {b0.x, b0.y, b0.z, b0.w, b1.x, b1.y, b1.z, b1.w};
#pragma unroll
            for (int i = 0; i < 8; i++)
#pragma unroll
                for (int j = 0; j < 8; j++) acc[i][j] = fmaf(av[i], bv[j], acc[i][j]);
        }
        __syncthreads();
    }
#pragma unroll
    for (int i = 0; i < 8; i++) {
        int gm = mtb * 128 + tm * 8 + i;
        if (gm < M) {
            int bb = gm / len, tt = gm - bb * len;
            float* Cp = xg + ((size_t)(d * B + bb) * L + tt) * G4 + gbase + tn * 8;
            float4 v0; v0.x = acc[i][0]; v0.y = acc[i][1]; v0.z = acc[i][2]; v0.w = acc[i][3];
            float4 v1; v1.x = acc[i][4]; v1.y = acc[i][5]; v1.z = acc[i][6]; v1.w = acc[i][7];
            *(float4*)&Cp[0] = v0;
            *(float4*)&Cp[4] = v1;
        }
    }
}

// ---------------- persistent: all 64 iterations, NaN-poison dataflow steps ----
// 256 blocks x 256 threads. block = (jg, sg, d). h: [s][d][B][H], poison-armed.
__global__ __launch_bounds__(256, 1) void k_persist(
        float* __restrict__ xg, const float* __restrict__ wtHH,
        const float* __restrict__ bias_f, const float* __restrict__ bias_b,
        const float* __restrict__ ow, const float* __restrict__ h0,
        const float* __restrict__ c0, float* __restrict__ hst,
        double* __restrict__ o_part, const float* __restrict__ ob,
        float* __restrict__ exb0, float* __restrict__ exb1,
        float* __restrict__ dec, float* __restrict__ units,
        float* __restrict__ out_or, float* __restrict__ out_ex,
        int* flags) {
    __shared__ __align__(16) float hs[256 * 16];     // 16KB
    __shared__ __align__(16) float pb[8 * 16 * 68];  // 34.8KB
    __shared__ float osh[68];
    __shared__ float dsh[64];
    __shared__ float dsh2[64];
    int tid = threadIdx.x;
    int bid = blockIdx.x;
    int jg = bid & 15, sgd = bid >> 4;
    int sg = sgd & 7, d = sgd >> 3;
    int b0 = sg * 16, j0 = jg * 16;
    const size_t HB = (size_t)2 * B * H;             // per-step h stride

    int* dflag = flags;
    int* dgen  = flags + 4096;
    int dph = 0;

    // W_hh slice resident in registers for the whole kernel
    float4 wreg[16];
    {
        const float4* wp = (const float4*)(wtHH + ((size_t)(d * 16 + jg) * 256 + tid) * 64);
#pragma unroll
        for (int m = 0; m < 16; m++) wreg[m] = wp[m];
    }
    // hoisted per-thread constants
    int bF = tid >> 4, jjF = tid & 15;
    int bG = b0 + bF, jG = j0 + jjF;
    const float* biasp = d ? bias_b : bias_f;
    float bias4[4] = { biasp[jG], biasp[256 + jG], biasp[512 + jG], biasp[768 + jG] };
    float owv = ow[d * H + jG];
    float c0v = c0[d * H + jG];
    // stage mapping + h0 staging values
    int bS = tid & 15, kc = tid >> 4;
    int swz = (((bS >> 2) ^ (kc & 3)) << 2) + (bS & 3);
    float4 h0s[4];
#pragma unroll
    for (int i4 = 0; i4 < 4; i4++)
        h0s[i4] = *(const float4*)&h0[d * H + kc * 16 + i4 * 4];
    const float* hstb = hst + ((size_t)(d * B + b0 + bS)) * H + kc * 16;
    float*       hwr  = hst + ((size_t)(d * B + bG)) * H + jG;
    float c_reg = 0.f;

    for (int it = 0; it < 64; ++it) {
        int len = 64 - it;
        int offL = len * (len - 1) / 2;
        int n = len - 1;
        const float* exs = (it & 1) ? exb1 : exb0;
        float* exd = (it & 1) ? exb0 : exb1;

        // ---- timestep chain (no barriers; NaN-poison dataflow) ----
        for (int s = 0; s < len; ++s) {
            int t = d ? (n - s) : s;
            // prefetch xg for this step (plain cached; fenced at iter boundary)
            size_t xgo = (((size_t)(d * B + bG)) * L + t) * G4 + jG;
            float x0 = xg[xgo], x1 = xg[xgo + 256], x2 = xg[xgo + 512], x3 = xg[xgo + 768];
            // stage h
            if (s == 0) {
#pragma unroll
                for (int i4 = 0; i4 < 4; i4++) {
                    int kk = kc * 16 + i4 * 4;
                    hs[(kk + 0) * 16 + swz] = h0s[i4].x;
                    hs[(kk + 1) * 16 + swz] = h0s[i4].y;
                    hs[(kk + 2) * 16 + swz] = h0s[i4].z;
                    hs[(kk + 3) * 16 + swz] = h0s[i4].w;
                }
            } else {
                const float* hp = hstb + (size_t)(s - 1) * HB;
                fx4 v0, v1, v2, v3;
                do { ld4x4_sc(hp, v0, v1, v2, v3); }
                while (any_nan(v0) | any_nan(v1) | any_nan(v2) | any_nan(v3));
                float arr[16] = { v0[0], v0[1], v0[2], v0[3], v1[0], v1[1], v1[2], v1[3],
                                  v2[0], v2[1], v2[2], v2[3], v3[0], v3[1], v3[2], v3[3] };
#pragma unroll
                for (int i = 0; i < 16; i++)
                    hs[(kc * 16 + i) * 16 + swz] = arr[i];
            }
            __syncthreads();
            {   // dot
                int jj = tid & 15, kseg = tid >> 4;
                int ks3 = kseg & 3;
                float acc[4][16];
#pragma unroll
                for (int q = 0; q < 4; q++)
#pragma unroll
                    for (int u = 0; u < 16; u++) acc[q][u] = 0.f;
#pragma unroll
                for (int i4 = 0; i4 < 4; i4++) {
#pragma unroll
                    for (int c = 0; c < 4; c++) {
                        int k = (kseg << 4) + (i4 << 2) + c;
                        const float* hb = &hs[k << 4];
                        float4 hv[4];
#pragma unroll
                        for (int bq = 0; bq < 4; bq++)
                            hv[bq] = *(const float4*)&hb[((bq ^ ks3) << 2)];
#pragma unroll
                        for (int q = 0; q < 4; q++) {
                            float4 wv = wreg[q * 4 + i4];
                            float w = (c == 0) ? wv.x : (c == 1) ? wv.y : (c == 2) ? wv.z : wv.w;
#pragma unroll
                            for (int bq = 0; bq < 4; bq++) {
                                acc[q][bq * 4 + 0] = fmaf(hv[bq].x, w, acc[q][bq * 4 + 0]);
                                acc[q][bq * 4 + 1] = fmaf(hv[bq].y, w, acc[q][bq * 4 + 1]);
                                acc[q][bq * 4 + 2] = fmaf(hv[bq].z, w, acc[q][bq * 4 + 2]);
                                acc[q][bq * 4 + 3] = fmaf(hv[bq].w, w, acc[q][bq * 4 + 3]);
                            }
                        }
                    }
                }
#pragma unroll
                for (int q = 0; q < 4; q++)
#pragma unroll
                    for (int u = 0; u < 16; u++) acc[q][u] += __shfl_xor(acc[q][u], 32);
                if (!(tid & 32)) {
                    int slice = ((tid >> 6) << 1) | ((tid >> 4) & 1);
                    float* pbp = &pb[(slice * 16 + jj) * 68];
#pragma unroll
                    for (int bb = 0; bb < 16; bb++) {
                        float4 v; v.x = acc[0][bb]; v.y = acc[1][bb]; v.z = acc[2][bb]; v.w = acc[3][bb];
                        *(float4*)&pbp[bb * 4] = v;
                    }
                }
            }
            __syncthreads();
            {   // finalize
                float g4[4] = {0.f, 0.f, 0.f, 0.f};
#pragma unroll
                for (int sl = 0; sl < 8; sl++) {
                    float4 pv = *(const float4*)&pb[(sl * 16 + jjF) * 68 + bF * 4];
                    g4[0] += pv.x; g4[1] += pv.y; g4[2] += pv.z; g4[3] += pv.w;
                }
                float g0 = x0 + bias4[0] + g4[0];
                float g1 = x1 + bias4[1] + g4[1];
                float g2 = x2 + bias4[2] + g4[2];
                float g3 = x3 + bias4[3] + g4[3];
                float c_old = (s == 0) ? c0v : c_reg;
                float ig = sigf(g0);
                float fg = sigf(g1);
                float gv = tanhf(g2);
                float og = sigf(g3);
                float c = fg * c_old + ig * gv;
                float h = og * tanhf(c);
                c_reg = c;
                stg_sc_f32(hwr + (size_t)s * HB, h);
                double contrib = (double)h * (double)owv;
#pragma unroll
                for (int off = 8; off > 0; off >>= 1) contrib += __shfl_xor(contrib, off, 16);
                if (jjF == 0) stg_sc_f64(&o_part[(((size_t)(d * 16 + jg)) * B + bG) * L + t], contrib);
            }
            __syncthreads();
        }
        ++dph; grid_barrier2(dflag, dgen, bid, dph);

        // ---- orient + decisions ----
        if (bid < 128) {
            int b = bid;
            float oval = 0.f, exval = 0.f;
            if (tid < len) {
                double sum = (double)ob[0];
#pragma unroll 4
                for (int i = 0; i < 32; i++) sum += o_part[((size_t)i * B + b) * L + tid];
                oval = (float)sum;
                osh[tid] = oval;
                exval = exs[b * L + tid];
                stg_sc_f32(out_or + (size_t)b * TOTROWS + offL + tid, oval);
                stg_sc_f32(out_ex + (size_t)b * TOTROWS + offL + tid, exval);
            }
            __syncthreads();
            if (tid < len - 1) {
                float on  = osh[tid + 1];
                float exn = exs[b * L + tid + 1];
                float lw = (oval > 0.f && exval != 0.f) ? 1.f : 0.f;
                float rw = (!(on > 0.f) && exn != 0.f) ? 1.f : 0.f;
                stg_sc_f32(dec + b * L + tid, lw + 2.f * rw);
                stg_sc_f32(exd + b * L + tid, ((lw + rw) > 0.f) ? 1.f : 0.f);
            }
        }
        ++dph; grid_barrier2(dflag, dgen, bid, dph);

        // ---- merge units + xg, and re-arm h poison for next iteration ----
        if (len > 1) {
            int bu = bid >> 1;        // units sample
            int b2 = bid & 127;       // xg sample
            if (tid < n) dsh[tid]  = dec[bu * L + tid];
            if (tid < n) dsh2[tid] = dec[b2 * L + tid];
            __syncthreads();
            {   // units: column (bu, k)
                int k = ((bid & 1) << 8) + tid;
                const float* src = units + ((size_t)bu * TOTROWS + offL) * D + k;
                float* dst = units + ((size_t)bu * TOTROWS + (offL - n)) * D + k;
                float cur = src[0];
                int tt = 0;
                while (tt < n) {
                    int m = (n - tt < 8) ? (n - tt) : 8;
                    float nx[8];
#pragma unroll
                    for (int i = 0; i < 8; i++) if (i < m) nx[i] = src[(size_t)(tt + i + 1) * D];
#pragma unroll
                    for (int i = 0; i < 8; i++) if (i < m) {
                        int dv = (int)dsh[tt + i];
                        stg_sc_f32(dst + (size_t)(tt + i) * D,
                                   (float)(dv & 1) * cur + (float)(dv >> 1) * nx[i]);
                        cur = nx[i];
                    }
                    tt += m;
                }
            }
            {   // xg: block = (d2,b2), float4 per thread
                int d2 = bid >> 7;
                float* base = xg + ((size_t)(d2 * B + b2) * L) * G4 + tid * 4;
                float4 cur = *(const float4*)base;
                int tt = 0;
                while (tt < n) {
                    int m = (n - tt < 8) ? (n - tt) : 8;
                    float4 nx[8];
#pragma unroll
                    for (int i = 0; i < 8; i++) if (i < m)
                        nx[i] = *(const float4*)(base + (size_t)(tt + i + 1) * G4);
#pragma unroll
                    for (int i = 0; i < 8; i++) if (i < m) {
                        int dv = (int)dsh2[tt + i];
                        float flw = (float)(dv & 1), frw = (float)(dv >> 1);
                        float4 o;
                        o.x = flw * cur.x + frw * nx[i].x;
                        o.y = flw * cur.y + frw * nx[i].y;
                        o.z = flw * cur.z + frw * nx[i].z;
                        o.w = flw * cur.w + frw * nx[i].w;
                        stg_sc_f4(base + (size_t)(tt + i) * G4, o);
                        cur = nx[i];
                    }
                    tt += m;
                }
            }
            {   // poison own (b,j) h-tile for next iteration's slices [0, n)
                float qn = __uint_as_float(0x7fc00000u);
                for (int s2 = 0; s2 < n; ++s2)
                    stg_sc_f32(hwr + (size_t)s2 * HB, qn);
            }
            ++dph; grid_barrier2(dflag, dgen, bid, dph);
        }
    }
}

extern "C" void kernel_launch(void* const* d_in, const int* in_sizes, int n_in,
                              void* d_out, int out_size, void* d_ws, size_t ws_size,
                              hipStream_t stream) {
    const int*   ex_in   = (const int*)d_in[0];
    const float* uh_in   = (const float*)d_in[1];
    const float* w_ih_f  = (const float*)d_in[2];
    const float* w_hh_f  = (const float*)d_in[3];
    const float* b_f     = (const float*)d_in[4];
    const float* w_ih_b  = (const float*)d_in[5];
    const float* w_hh_b  = (const float*)d_in[6];
    const float* b_b     = (const float*)d_in[7];
    const float* orientw = (const float*)d_in[8];
    const float* orientb = (const float*)d_in[9];
    const float* h0      = (const float*)d_in[10];
    const float* c0      = (const float*)d_in[11];

    float* units  = (float*)d_out;
    float* out_or = units + (size_t)B * TOTROWS * D;
    float* out_ex = out_or + (size_t)B * TOTROWS;

    float* xg    = (float*)d_ws;                       // 16,777,216 f (64MB)
    float* wihT  = xg + (size_t)2 * B * L * G4;        // 1,048,576 f
    float* wtHH  = wihT + (size_t)1048576;             // 524,288 f
    float* hst   = wtHH + (size_t)524288;              // 64 * 2*B*H = 4,194,304 f (16MB)
    float* dec   = hst + (size_t)64 * 2 * B * H;       // 8,192 f
    float* exb0  = dec + B * L;                        // 8,192 f
    float* exb1  = exb0 + B * L;                       // 8,192 f
    double* opart = (double*)(exb1 + B * L);           // 262,144 d (2MB)
    int*   flags = (int*)(opart + 262144);             // 8,192 ints

    k_init<<<4096, 256, 0, stream>>>(ex_in, uh_in, units, exb0, hst, flags);
    k_wprep_ih<<<4096, 256, 0, stream>>>(w_ih_f, w_ih_b, wihT);
    k_wprep_hh<<<2048, 256, 0, stream>>>(w_hh_f, w_hh_b, wtHH);
    k_xg<<<dim3(16, 64), 256, 0, stream>>>(units, wihT, xg, 64, 2016);
    k_persist<<<NBLK, 256, 0, stream>>>(xg, wtHH, b_f, b_b, orientw, h0, c0,
                                        hst, opart, orientb,
                                        exb0, exb1, dec, units, out_or, out_ex, flags);
    (void)in_sizes; (void)n_in; (void)out_size; (void)ws_size;
}